// Round 1
// baseline (423.330 us; speedup 1.0000x reference)
//
#include <hip/hip_runtime.h>
#include <hip/hip_fp16.h>

typedef _Float16 half8 __attribute__((ext_vector_type(8)));
typedef float f32x4 __attribute__((ext_vector_type(4)));

#define HID 128
#define NDIM 16
#define NCONV 8

static __device__ __forceinline__ half8 load_h8(const _Float16* p) {
    return *(const half8*)p;
}

// ---------------- weight prep: f16 transposed weights ----------------
// WABT[l] : [256][128] f16. rows j<128:  W1A_T[j][k] = W1[l][k][j] - W1[l][128+k][j]
//                           rows 128+j:  W1B_T[j][k] = W1[l][128+k][j]
// W2T[l]  : [128][128] f16. W2T[j][k] = W2[l][k][j]
__global__ void prep_weights(const float* __restrict__ W1, const float* __restrict__ W2,
                             _Float16* __restrict__ WABT, _Float16* __restrict__ W2T) {
    int idx = blockIdx.x * blockDim.x + threadIdx.x;
    int total = NCONV * HID * HID;
    if (idx >= total) return;
    int l = idx / (HID * HID);
    int r = idx % (HID * HID);
    int j = r / HID;
    int k = r % HID;
    const float* w1 = W1 + (size_t)l * 2 * HID * HID;
    float top = w1[k * HID + j];
    float bot = w1[(HID + k) * HID + j];
    _Float16* wab = WABT + (size_t)l * 2 * HID * HID;
    wab[j * HID + k] = (_Float16)(top - bot);
    wab[(HID + j) * HID + k] = (_Float16)bot;
    const float* w2 = W2 + (size_t)l * HID * HID;
    W2T[(size_t)l * HID * HID + j * HID + k] = (_Float16)w2[k * HID + j];
}

// ---------------- time embedding ----------------
__global__ void time_emb_kernel(const float* __restrict__ t, const float* __restrict__ tpW,
                                const float* __restrict__ tpb, float* __restrict__ temb) {
    __shared__ float sc[64];
    int i = threadIdx.x;
    float tv = t[0];
    if (i < 32) {
        float f = expf(-4.0f + 8.0f * (float)i / 31.0f);
        sc[i] = sinf(tv * f);
        sc[32 + i] = cosf(tv * f);
    }
    __syncthreads();
    if (i < 16) {
        float acc = tpb[i];
        for (int k = 0; k < 64; k++) acc += sc[k] * tpW[k * NDIM + i];
        temb[i] = acc;
    }
}

// ---------------- node embedding: h = (x + temb) @ neW + neb -> f16 ----------------
__global__ void node_emb_kernel(const float* __restrict__ x, const float* __restrict__ temb,
                                const float* __restrict__ W, const float* __restrict__ b,
                                _Float16* __restrict__ h16, int n) {
    __shared__ float sx[NDIM];
    int node = blockIdx.x;
    if (node >= n) return;
    int j = threadIdx.x;
    if (j < NDIM) sx[j] = x[(size_t)node * NDIM + j] + temb[j];
    __syncthreads();
    float acc = b[j];
    #pragma unroll
    for (int d = 0; d < NDIM; d++) acc += sx[d] * W[d * HID + j];
    h16[(size_t)node * HID + j] = (_Float16)acc;
}

// ---------------- CSR build ----------------
__global__ void zero_int(int* __restrict__ p, int n) {
    int i = blockIdx.x * blockDim.x + threadIdx.x;
    if (i < n) p[i] = 0;
}

__global__ void count_deg(const int* __restrict__ ei, int* __restrict__ deg, int E) {
    int e = blockIdx.x * blockDim.x + threadIdx.x;
    if (e < E) atomicAdd(&deg[ei[E + e]], 1);   // dst row
}

__global__ void scan_csr(const int* __restrict__ deg, int* __restrict__ rowptr,
                         int* __restrict__ cursor, int n) {
    __shared__ int part[1024];
    int t = threadIdx.x;
    int chunk = (n + 1023) / 1024;
    int base = t * chunk;
    int s = 0;
    for (int i = 0; i < chunk; i++) {
        int id = base + i;
        if (id < n) s += deg[id];
    }
    part[t] = s;
    __syncthreads();
    for (int off = 1; off < 1024; off <<= 1) {
        int v = 0;
        if (t >= off) v = part[t - off];
        __syncthreads();
        part[t] += v;
        __syncthreads();
    }
    int pre = (t == 0) ? 0 : part[t - 1];
    for (int i = 0; i < chunk; i++) {
        int id = base + i;
        if (id < n) {
            rowptr[id] = pre;
            cursor[id] = pre;
            pre += deg[id];
        }
    }
    if (t == 1023) rowptr[n] = part[1023];
}

__global__ void fill_csr(const int* __restrict__ ei, int* __restrict__ cursor,
                         int* __restrict__ elist, int E) {
    int e = blockIdx.x * blockDim.x + threadIdx.x;
    if (e < E) {
        int d = ei[E + e];
        int pos = atomicAdd(&cursor[d], 1);
        elist[pos] = ei[e];   // src
    }
}

// ---------------- AB tables: AB[n] = [ h@W1A + b1 | h@W1B ]  (f16, [N][256]) ----------------
__global__ __launch_bounds__(256) void ab_gemm(const _Float16* __restrict__ h16,
                                               const _Float16* __restrict__ WABT_l,
                                               const float* __restrict__ b1_l,
                                               _Float16* __restrict__ AB, int n) {
    int wid = (blockIdx.x * blockDim.x + threadIdx.x) >> 6;
    int lane = threadIdx.x & 63;
    int nmt = (n + 15) / 16;
    if (wid >= nmt * 16) return;
    int mt = wid >> 4;       // 16 j-tiles per m-tile
    int jt = wid & 15;
    int c = lane & 15;
    int kq = lane >> 4;

    int arow = mt * 16 + c;
    half8 a[4];
    #pragma unroll
    for (int kb = 0; kb < 4; kb++) {
        if (arow < n) a[kb] = load_h8(h16 + (size_t)arow * HID + kb * 32 + kq * 8);
        else          a[kb] = (half8)(_Float16)0;
    }
    int wrow = jt * 16 + c;  // output column (0..255)
    half8 b[4];
    #pragma unroll
    for (int kb = 0; kb < 4; kb++)
        b[kb] = load_h8(WABT_l + (size_t)wrow * HID + kb * 32 + kq * 8);

    f32x4 acc = {0.f, 0.f, 0.f, 0.f};
    #pragma unroll
    for (int kb = 0; kb < 4; kb++)
        acc = __builtin_amdgcn_mfma_f32_16x16x32_f16(a[kb], b[kb], acc, 0, 0, 0);

    int col = jt * 16 + c;
    float bias = (col < HID) ? b1_l[col] : 0.f;
    #pragma unroll
    for (int r = 0; r < 4; r++) {
        int row = mt * 16 + kq * 4 + r;
        if (row < n) AB[(size_t)row * 256 + col] = (_Float16)(acc[r] + bias);
    }
}

// ---------------- EdgeConv: out[v][j] = max_e relu(A[v]+B[src_e]) @ W2 + b2 ----------------
__global__ __launch_bounds__(256, 2) void edge_conv(const _Float16* __restrict__ AB,
                                                    const _Float16* __restrict__ W2T_l,
                                                    const float* __restrict__ b2_l,
                                                    const int* __restrict__ rowptr,
                                                    const int* __restrict__ elist,
                                                    _Float16* __restrict__ hout, int n) {
    int lane = threadIdx.x & 63;
    int gw = (blockIdx.x * blockDim.x + threadIdx.x) >> 6;
    int nw = (gridDim.x * blockDim.x) >> 6;
    int c = lane & 15;
    int kq = lane >> 4;

    // W2 B-fragments resident in VGPRs: col = cb*16+c, k = kb*32 + kq*8 + 0..7
    half8 w2f[8][4];
    #pragma unroll
    for (int cb = 0; cb < 8; cb++)
        #pragma unroll
        for (int kb = 0; kb < 4; kb++)
            w2f[cb][kb] = load_h8(W2T_l + (size_t)(cb * 16 + c) * HID + kb * 32 + kq * 8);
    float b2v[8];
    #pragma unroll
    for (int cb = 0; cb < 8; cb++) b2v[cb] = b2_l[cb * 16 + c];

    for (int v = gw; v < n; v += nw) {
        int rbeg = rowptr[v];
        int deg = rowptr[v + 1] - rbeg;     // real in-edges; +1 implicit self-loop
        int ntile = (deg + 1 + 15) >> 4;

        half8 af[4];
        #pragma unroll
        for (int kb = 0; kb < 4; kb++)
            af[kb] = load_h8(AB + (size_t)v * 256 + kb * 32 + kq * 8);

        f32x4 macc[8];
        #pragma unroll
        for (int cb = 0; cb < 8; cb++) {
            macc[cb][0] = -3.0e38f; macc[cb][1] = -3.0e38f;
            macc[cb][2] = -3.0e38f; macc[cb][3] = -3.0e38f;
        }

        for (int tI = 0; tI < ntile; tI++) {
            int gidx = tI * 16 + c;                       // this lane's A-frag row = its edge
            int src = (gidx < deg) ? elist[rbeg + gidx] : v;   // pad with self-loop (max-invariant)

            half8 hf[4];
            #pragma unroll
            for (int kb = 0; kb < 4; kb++) {
                half8 s = af[kb] + load_h8(AB + (size_t)src * 256 + 128 + kb * 32 + kq * 8);
                #pragma unroll
                for (int e = 0; e < 8; e++) s[e] = (s[e] > (_Float16)0) ? s[e] : (_Float16)0;
                hf[kb] = s;
            }
            #pragma unroll
            for (int cb = 0; cb < 8; cb++) {
                f32x4 d = {0.f, 0.f, 0.f, 0.f};
                #pragma unroll
                for (int kb = 0; kb < 4; kb++)
                    d = __builtin_amdgcn_mfma_f32_16x16x32_f16(hf[kb], w2f[cb][kb], d, 0, 0, 0);
                #pragma unroll
                for (int r = 0; r < 4; r++) macc[cb][r] = fmaxf(macc[cb][r], d[r]);
            }
        }

        #pragma unroll
        for (int cb = 0; cb < 8; cb++) {
            float m = fmaxf(fmaxf(macc[cb][0], macc[cb][1]), fmaxf(macc[cb][2], macc[cb][3]));
            m = fmaxf(m, __shfl_xor(m, 16));
            m = fmaxf(m, __shfl_xor(m, 32));
            m += b2v[cb];
            if (lane < 16) hout[(size_t)v * HID + cb * 16 + c] = (_Float16)m;
        }
    }
}

// ---------------- mid FC (enc_fc), in-place row-local: h = h @ W + b ----------------
__global__ void fc_mid(_Float16* __restrict__ h16, const float* __restrict__ W,
                       const float* __restrict__ b, int n) {
    __shared__ float row[HID];
    int node = blockIdx.x;
    if (node >= n) return;
    int j = threadIdx.x;
    row[j] = (float)h16[(size_t)node * HID + j];
    __syncthreads();
    float acc = b[j];
    for (int k = 0; k < HID; k++) acc += row[k] * W[k * HID + j];
    h16[(size_t)node * HID + j] = (_Float16)acc;
}

// ---------------- decoder FC: out = h @ dW + db  (fp32 out [N][16]) ----------------
__global__ void fc_dec(const _Float16* __restrict__ h16, const float* __restrict__ W,
                       const float* __restrict__ b, float* __restrict__ out, int n) {
    __shared__ float row[HID];
    __shared__ float part[64];
    int node = blockIdx.x;
    if (node >= n) return;
    int t = threadIdx.x;
    row[t] = (float)h16[(size_t)node * HID + t];
    row[64 + t] = (float)h16[(size_t)node * HID + 64 + t];
    __syncthreads();
    int j = t & 15;
    int ks = t >> 4;   // 0..3, each covers 32 k
    float p = 0.f;
    for (int k = ks * 32; k < ks * 32 + 32; k++) p += row[k] * W[k * NDIM + j];
    part[t] = p;
    __syncthreads();
    if (t < 16) {
        float o = b[j] + part[j] + part[16 + j] + part[32 + j] + part[48 + j];
        out[(size_t)node * NDIM + j] = o;
    }
}

// ---------------- host ----------------
extern "C" void kernel_launch(void* const* d_in, const int* in_sizes, int n_in,
                              void* d_out, int out_size, void* d_ws, size_t ws_size,
                              hipStream_t stream) {
    const float* x   = (const float*)d_in[0];
    const int*   ei  = (const int*)d_in[1];
    const float* t   = (const float*)d_in[2];
    const float* neW = (const float*)d_in[3];
    const float* neb = (const float*)d_in[4];
    const float* cW1 = (const float*)d_in[5];
    const float* cb1 = (const float*)d_in[6];
    const float* cW2 = (const float*)d_in[7];
    const float* cb2 = (const float*)d_in[8];
    const float* eW  = (const float*)d_in[9];
    const float* eb  = (const float*)d_in[10];
    const float* dW  = (const float*)d_in[11];
    const float* db  = (const float*)d_in[12];
    const float* tpW = (const float*)d_in[13];
    const float* tpb = (const float*)d_in[14];

    int N = in_sizes[0] / NDIM;
    int E = in_sizes[1] / 2;

    char* w = (char*)d_ws;
    auto alloc = [&](size_t bytes) {
        void* p = (void*)w;
        w += (bytes + 255) & ~(size_t)255;
        return p;
    };
    float*     temb   = (float*)alloc(64 * 4);
    _Float16*  h16    = (_Float16*)alloc((size_t)N * HID * 2);
    _Float16*  AB     = (_Float16*)alloc((size_t)N * 2 * HID * 2);
    _Float16*  WABT   = (_Float16*)alloc((size_t)NCONV * 2 * HID * HID * 2);
    _Float16*  W2T    = (_Float16*)alloc((size_t)NCONV * HID * HID * 2);
    int*       deg    = (int*)alloc((size_t)N * 4);
    int*       rowptr = (int*)alloc((size_t)(N + 1) * 4);
    int*       cursor = (int*)alloc((size_t)N * 4);
    int*       elist  = (int*)alloc((size_t)E * 4);

    // weights + time embedding + node embedding
    prep_weights<<<(NCONV * HID * HID + 255) / 256, 256, 0, stream>>>(cW1, cW2, WABT, W2T);
    time_emb_kernel<<<1, 64, 0, stream>>>(t, tpW, tpb, temb);
    node_emb_kernel<<<N, HID, 0, stream>>>(x, temb, neW, neb, h16, N);

    // CSR by dst
    zero_int<<<(N + 255) / 256, 256, 0, stream>>>(deg, N);
    count_deg<<<(E + 255) / 256, 256, 0, stream>>>(ei, deg, E);
    scan_csr<<<1, 1024, 0, stream>>>(deg, rowptr, cursor, N);
    fill_csr<<<(E + 255) / 256, 256, 0, stream>>>(ei, cursor, elist, E);

    int nmt = (N + 15) / 16;
    int ab_waves = nmt * 16;
    int ab_blocks = (ab_waves + 3) / 4;

    for (int l = 0; l < NCONV; l++) {
        if (l == 4) fc_mid<<<N, HID, 0, stream>>>(h16, eW, eb, N);
        ab_gemm<<<ab_blocks, 256, 0, stream>>>(h16, WABT + (size_t)l * 2 * HID * HID,
                                               cb1 + (size_t)l * HID, AB, N);
        edge_conv<<<512, 256, 0, stream>>>(AB, W2T + (size_t)l * HID * HID,
                                           cb2 + (size_t)l * HID, rowptr, elist, h16, N);
    }

    fc_dec<<<N, HID, 0, stream>>>(h16, dW, db, (float*)d_out, N);
}